// Round 6
// baseline (277.283 us; speedup 1.0000x reference)
//
#include <hip/hip_runtime.h>
#include <hip/hip_bf16.h>

#define S_LEN 4096
#define HID 768
#define NHEAD 12
#define HL 64
#define QB 64   // q rows per block: 768 blocks, 3 blocks/CU
#define ORST 68 // O-reduction LDS row stride (64 + 4 pad): 2-way banks (free)

typedef __attribute__((ext_vector_type(8))) short short8;
typedef __attribute__((ext_vector_type(4))) short s16x4;
typedef __attribute__((ext_vector_type(4))) float f32x4;
using bf16 = __hip_bfloat16;

__device__ __forceinline__ void gl2lds16(const void* g, void* l) {
  __builtin_amdgcn_global_load_lds((__attribute__((address_space(1))) void*)(g),
                                   (__attribute__((address_space(3))) void*)(l),
                                   16, 0, 0);
}

__device__ __forceinline__ f32x4 mfma_bf16(short8 a, short8 b, f32x4 c) {
  return __builtin_amdgcn_mfma_f32_16x16x32_bf16(a, b, c, 0, 0, 0);
}

// K=16 bf16 MFMA. v7's raw asm NaN'd: (1) "=v" without early-clobber lets D
// alias SrcA/B (illegal for multi-pass MFMA); (2) no s_nop hazard waits for
// VALU-write -> MFMA-read (compiler only inserts them for builtins). Prefer
// the carried-forward gfx90a builtin (instruction exists in gfx950 ISA);
// hardened asm fallback: early-clobber D + conservative wait states.
__device__ __forceinline__ f32x4 mfma16_bf16(s16x4 a, s16x4 b, f32x4 c) {
#if __has_builtin(__builtin_amdgcn_mfma_f32_16x16x16bf16_1k)
  return __builtin_amdgcn_mfma_f32_16x16x16bf16_1k(a, b, c, 0, 0, 0);
#elif __has_builtin(__builtin_amdgcn_mfma_f32_16x16x16_bf16)
  return __builtin_amdgcn_mfma_f32_16x16x16_bf16(a, b, c, 0, 0, 0);
#else
  f32x4 d;
  asm volatile(
      "s_nop 1\n\t"
      "v_mfma_f32_16x16x16_bf16 %0, %1, %2, %3\n\t"
      "s_nop 7\n\t"
      "s_nop 2"
      : "=&v"(d)
      : "v"(a), "v"(b), "v"(c));
  return d;
#endif
}

__device__ __forceinline__ void storeC(float* C, long idx, float v) { C[idx] = v; }
__device__ __forceinline__ void storeC(bf16* C, long idx, float v) { C[idx] = __float2bfloat16(v); }

// ---------------- fp32 -> bf16 convert (x + 4 weights, fused) ----------------
__global__ __launch_bounds__(256) void cvt_all(
    const float* __restrict__ x, const float* __restrict__ wq,
    const float* __restrict__ wk, const float* __restrict__ wv,
    const float* __restrict__ wfc, bf16* __restrict__ xb, bf16* __restrict__ wqb,
    bf16* __restrict__ wkb, bf16* __restrict__ wvb, bf16* __restrict__ wfcb) {
  const long NX = (long)S_LEN * HID;
  const long NW = (long)HID * HID;
  long i = ((long)blockIdx.x * 256 + threadIdx.x) * 4;
  const float* src;
  bf16* dst;
  long off;
  if (i < NX) {
    src = x; dst = xb; off = i;
  } else {
    long j = i - NX;
    int wsel = (int)(j / NW);
    off = j - (long)wsel * NW;
    src = wsel == 0 ? wq : wsel == 1 ? wk : wsel == 2 ? wv : wfc;
    dst = wsel == 0 ? wqb : wsel == 1 ? wkb : wsel == 2 ? wvb : wfcb;
  }
  float4 v = *(const float4*)(src + off);
  bf16 h0 = __float2bfloat16(v.x), h1 = __float2bfloat16(v.y);
  bf16 h2 = __float2bfloat16(v.z), h3 = __float2bfloat16(v.w);
  ushort4 o;
  o.x = *(unsigned short*)&h0; o.y = *(unsigned short*)&h1;
  o.z = *(unsigned short*)&h2; o.w = *(unsigned short*)&h3;
  *(ushort4*)(dst + off) = o;
}

// ---------------- GEMM: C[M x 768] = scale * A[M x 768] * B[768 x 768]^T ------
template <typename OT>
__global__ __launch_bounds__(256) void gemm_bt(
    const bf16* __restrict__ A, const bf16* __restrict__ B0,
    const bf16* __restrict__ B1, const bf16* __restrict__ B2,
    OT* __restrict__ C0, OT* __restrict__ C1, OT* __restrict__ C2, float qscale) {
  constexpr int K = HID;
  __shared__ __align__(16) bf16 As[128 * 32];
  __shared__ __align__(16) bf16 Bs[128 * 32];
  const int z = blockIdx.z;
  const bf16* B = (z == 0) ? B0 : (z == 1) ? B1 : B2;
  OT* C = (z == 0) ? C0 : (z == 1) ? C1 : C2;
  const float sc = (z == 0) ? qscale : 1.0f;
  const int bm = blockIdx.y, bn = blockIdx.x;
  const int t = threadIdx.x, lane = t & 63, w = t >> 6;
  const int wm = w >> 1, wn = w & 1;
  const int q4 = lane >> 4, c16 = lane & 15;
  const int srow = lane >> 2, scol = (lane & 3) * 8;
  const bf16* Ab = A + (long)bm * 128 * K;
  const bf16* Bb = B + (long)bn * 128 * K;
  f32x4 acc[4][4] = {};
  for (int k0 = 0; k0 < K; k0 += 32) {
#pragma unroll
    for (int r = 0; r < 2; ++r) {
      int rowb = r * 64 + w * 16;
      gl2lds16(Ab + (long)(rowb + srow) * K + k0 + scol, &As[rowb * 32]);
      gl2lds16(Bb + (long)(rowb + srow) * K + k0 + scol, &Bs[rowb * 32]);
    }
    __syncthreads();
    short8 af[4], bfv[4];
#pragma unroll
    for (int i = 0; i < 4; ++i)
      af[i] = *(const short8*)&As[(wm * 64 + i * 16 + c16) * 32 + q4 * 8];
#pragma unroll
    for (int j = 0; j < 4; ++j)
      bfv[j] = *(const short8*)&Bs[(wn * 64 + j * 16 + c16) * 32 + q4 * 8];
#pragma unroll
    for (int i = 0; i < 4; ++i)
#pragma unroll
      for (int j = 0; j < 4; ++j)
        acc[i][j] = mfma_bf16(af[i], bfv[j], acc[i][j]);
    __syncthreads();
  }
  const long crow0 = (long)bm * 128 + wm * 64;
  const int ccol0 = bn * 128 + wn * 64;
#pragma unroll
  for (int i = 0; i < 4; ++i)
#pragma unroll
    for (int j = 0; j < 4; ++j)
#pragma unroll
      for (int r = 0; r < 4; ++r) {
        long row = crow0 + i * 16 + q4 * 4 + r;
        int col = ccol0 + j * 16 + c16;
        storeC(C, row * HID + col, sc * acc[i][j][r]);
      }
}

// ---------------- final GEMM: 128x64 tile (384 blocks, better occupancy) ------
__global__ __launch_bounds__(256) void gemm_fc(const bf16* __restrict__ A,
                                               const bf16* __restrict__ B,
                                               float* __restrict__ C) {
  __shared__ __align__(16) bf16 As[128 * 32];
  __shared__ __align__(16) bf16 Bs[64 * 32];
  const int bm = blockIdx.y, bn = blockIdx.x;
  const int t = threadIdx.x, lane = t & 63, w = t >> 6;
  const int q4 = lane >> 4, c16 = lane & 15;
  const int srow = lane >> 2, scol = (lane & 3) * 8;
  const bf16* Ab = A + (long)bm * 128 * HID;
  const bf16* Bb = B + (long)bn * 64 * HID;
  f32x4 acc[2][4] = {};
  for (int k0 = 0; k0 < HID; k0 += 32) {
#pragma unroll
    for (int r = 0; r < 2; ++r) {
      int rowb = w * 32 + r * 16;
      gl2lds16(Ab + (long)(rowb + srow) * HID + k0 + scol, &As[rowb * 32]);
    }
    gl2lds16(Bb + (long)(w * 16 + srow) * HID + k0 + scol, &Bs[w * 16 * 32]);
    __syncthreads();
    short8 af[2], bfv[4];
#pragma unroll
    for (int i = 0; i < 2; ++i)
      af[i] = *(const short8*)&As[(w * 32 + i * 16 + c16) * 32 + q4 * 8];
#pragma unroll
    for (int j = 0; j < 4; ++j)
      bfv[j] = *(const short8*)&Bs[(j * 16 + c16) * 32 + q4 * 8];
#pragma unroll
    for (int i = 0; i < 2; ++i)
#pragma unroll
      for (int j = 0; j < 4; ++j)
        acc[i][j] = mfma_bf16(af[i], bfv[j], acc[i][j]);
    __syncthreads();
  }
#pragma unroll
  for (int i = 0; i < 2; ++i)
#pragma unroll
    for (int j = 0; j < 4; ++j)
#pragma unroll
      for (int r = 0; r < 4; ++r) {
        long row = (long)bm * 128 + w * 32 + i * 16 + q4 * 4 + r;
        int col = bn * 64 + j * 16 + c16;
        C[row * HID + col] = acc[i][j][r];
      }
}

// ---------------- V transpose: [4096][768] -> [768][4096] ----------------
__global__ __launch_bounds__(256) void transpose_v(const bf16* __restrict__ V,
                                                   bf16* __restrict__ Vt) {
  __shared__ unsigned short tile[64][65];
  const int bs = blockIdx.x * 64;
  const int be = blockIdx.y * 64;
  const int t = threadIdx.x;
#pragma unroll
  for (int p = 0; p < 4; ++p) {
    int i = p * 256 + t;
    int r = i >> 4;
    int c = (i & 15) * 4;
    ushort4 v = *(const ushort4*)((const unsigned short*)V + (long)(bs + r) * HID + be + c);
    tile[r][c] = v.x; tile[r][c + 1] = v.y; tile[r][c + 2] = v.z; tile[r][c + 3] = v.w;
  }
  __syncthreads();
#pragma unroll
  for (int p = 0; p < 4; ++p) {
    int i = p * 256 + t;
    int r = i >> 4;
    int c = (i & 15) * 4;
    ushort4 v;
    v.x = tile[c][r]; v.y = tile[c + 1][r]; v.z = tile[c + 2][r]; v.w = tile[c + 3][r];
    *(ushort4*)((unsigned short*)Vt + (long)(be + r) * S_LEN + bs + c) = v;
  }
}

// ---------------- flash attention v8: v7 structure + safe K=16 MFMA -----------
// v7's register-direct P path (wave-local kv stripes; QK C/D layout == K=16
// MFMA B-operand layout; full 64x64 O^T partial per wave; single epilogue
// reduction) NaN'd due to the raw asm MFMA (D/SrcA-B overlap + missing hazard
// nops). v8: identical structure, MFMA via builtin (or hardened asm fallback).
// Main loop: 24 MFMA + ~120 VALU + 6 vmem, 0 LDS ops, 0 barriers per wave-iter.
// XCD swizzle kept (K/V L2-local, FETCH 52->15MB proven in v6).
__global__ __launch_bounds__(256, 3) void flash_attn(const bf16* __restrict__ Q,
                                                     const bf16* __restrict__ Kg,
                                                     const bf16* __restrict__ Vt,
                                                     bf16* __restrict__ O) {
  __shared__ float Ored[64 * ORST];  // [w*16 + d'][q], 17.4 KB
  __shared__ float Lred[4][QB];
  const int i0 = blockIdx.x;
  const int xcd = i0 & 7, sb = i0 >> 3;
  const int pair = xcd >> 1;
  const int r2 = sb * 2 + (xcd & 1);
  const int h = pair * 3 + (r2 >> 6);
  const int qt = r2 & 63;
  const int t = threadIdx.x, lane = t & 63, w = t >> 6;
  const int q4 = lane >> 4, c16 = lane & 15;
  const int s0 = qt * QB;

  // Q B-frags, loop-invariant: row q = s0 + j*16 + c16, k-chunk = ks*32 + q4*8
  short8 qf[2][4];
  {
    const bf16* Qb = Q + (long)(s0 + c16) * HID + h * HL + q4 * 8;
#pragma unroll
    for (int j = 0; j < 4; ++j)
#pragma unroll
      for (int ks = 0; ks < 2; ++ks)
        qf[ks][j] = *(const short8*)(Qb + (long)j * 16 * HID + ks * 32);
  }
  // K A-frag base: row kv = kt*64 + w*16 + c16, k-chunk = ks*32 + q4*8
  const bf16* kp = Kg + (long)(w * 16 + c16) * HID + h * HL + q4 * 8;
  // V^T K=16 A-frag base: row d = i*16 + c16, k = kt*64 + w*16 + q4*4 + e
  const bf16* vbase = Vt + (long)(h * HL + c16) * S_LEN + w * 16 + q4 * 4;

  float l_part[4] = {0.f, 0.f, 0.f, 0.f};
  f32x4 o_acc[4][4] = {};  // [i = d-tile][j = q-tile], O^T partial (wave's kv)

  short8 kf0 = *(const short8*)(kp), kf1 = *(const short8*)(kp + 32);

  constexpr int NT = S_LEN / 64;
  for (int kt = 0; kt < NT; ++kt) {
    // ---- prefetch next K tile (consumed at next iter top) ----
    const bf16* kpn = (kt + 1 < NT) ? kp + 64 * HID : kp;
    short8 nk0 = *(const short8*)(kpn), nk1 = *(const short8*)(kpn + 32);
    // ---- current V^T frags (consumed after QK+exp: in-iter latency slack) ----
    s16x4 vf[4];
#pragma unroll
    for (int i = 0; i < 4; ++i)
      vf[i] = *(const s16x4*)(vbase + (long)i * 16 * S_LEN + kt * 64);

    // ---- S^T = K . Q^T : D[kv(wave's 16)][q 64] ----
    f32x4 sacc[4] = {};
#pragma unroll
    for (int j = 0; j < 4; ++j) sacc[j] = mfma_bf16(kf0, qf[0][j], sacc[j]);
#pragma unroll
    for (int j = 0; j < 4; ++j) sacc[j] = mfma_bf16(kf1, qf[1][j], sacc[j]);

    // ---- per q-tile: exp2 -> pack (IS the K=16 B-frag) -> PV, all in regs ----
#pragma unroll
    for (int j = 0; j < 4; ++j) {
      float p0 = __builtin_amdgcn_exp2f(sacc[j][0]);
      float p1 = __builtin_amdgcn_exp2f(sacc[j][1]);
      float p2 = __builtin_amdgcn_exp2f(sacc[j][2]);
      float p3 = __builtin_amdgcn_exp2f(sacc[j][3]);
      l_part[j] += (p0 + p1) + (p2 + p3);
      bf16 b0 = __float2bfloat16(p0), b1 = __float2bfloat16(p1);
      bf16 b2 = __float2bfloat16(p2), b3 = __float2bfloat16(p3);
      s16x4 pf;
      pf[0] = *(short*)&b0; pf[1] = *(short*)&b1;
      pf[2] = *(short*)&b2; pf[3] = *(short*)&b3;
      // O^T[d = i*16 + q4*4 + r][q = j*16 + c16] += V^T . P^T (K = wave's 16 kv)
#pragma unroll
      for (int i = 0; i < 4; ++i)
        o_acc[i][j] = mfma16_bf16(vf[i], pf, o_acc[i][j]);
    }

    kf0 = nk0; kf1 = nk1; kp = kpn;
  }

  // ---- l reduction: quad-sum (kv within wave) then cross-wave via LDS ----
#pragma unroll
  for (int j = 0; j < 4; ++j) {
    float s = l_part[j];
    s += __shfl_xor(s, 16, 64);
    s += __shfl_xor(s, 32, 64);
    Lred[w][j * 16 + c16] = s;  // all quads write same value: benign
  }
  __syncthreads();
  float rl[4];
#pragma unroll
  for (int j = 0; j < 4; ++j) {
    int q = j * 16 + c16;
    rl[j] = 1.0f / (Lred[0][q] + Lred[1][q] + Lred[2][q] + Lred[3][q]);
  }

  // ---- O^T cross-wave reduction: 4 rounds; round rd reduces d-tile rd, owned
  // by wave rd (normalize + pack + store). Banks: 2 lanes/bank (free). ----
#pragma unroll 1
  for (int rd = 0; rd < 4; ++rd) {
#pragma unroll
    for (int j = 0; j < 4; ++j)
#pragma unroll
      for (int r = 0; r < 4; ++r)
        Ored[(w * 16 + q4 * 4 + r) * ORST + j * 16 + c16] = o_acc[rd][j][r];
    __syncthreads();
    if (w == rd) {
#pragma unroll
      for (int j = 0; j < 4; ++j) {
        float v[4];
#pragma unroll
        for (int r = 0; r < 4; ++r) {
          int off = (q4 * 4 + r) * ORST + j * 16 + c16;
          v[r] = (Ored[off] + Ored[16 * ORST + off]) +
                 (Ored[32 * ORST + off] + Ored[48 * ORST + off]);
          v[r] *= rl[j];
        }
        bf16 b0 = __float2bfloat16(v[0]), b1 = __float2bfloat16(v[1]);
        bf16 b2 = __float2bfloat16(v[2]), b3 = __float2bfloat16(v[3]);
        short4 pk;
        pk.x = *(short*)&b0; pk.y = *(short*)&b1;
        pk.z = *(short*)&b2; pk.w = *(short*)&b3;
        // O[s0 + q][h*64 + d], d = rd*16 + q4*4 + r
        *(short4*)&O[(long)(s0 + j * 16 + c16) * HID + h * HL + rd * 16 + q4 * 4] = pk;
      }
    }
    __syncthreads();
  }
}

extern "C" void kernel_launch(void* const* d_in, const int* in_sizes, int n_in,
                              void* d_out, int out_size, void* d_ws, size_t ws_size,
                              hipStream_t stream) {
  const float* x = (const float*)d_in[0];
  const float* wq = (const float*)d_in[1];
  const float* wk = (const float*)d_in[2];
  const float* wv = (const float*)d_in[3];
  const float* wfc = (const float*)d_in[4];
  float* out = (float*)d_out;

  const long NBIG = (long)S_LEN * HID * sizeof(bf16);
  const long NWB = (long)HID * HID * sizeof(bf16);
  char* p = (char*)d_ws;
  bf16* xb = (bf16*)p;   p += NBIG;
  bf16* wqb = (bf16*)p;  p += NWB;
  bf16* wkb = (bf16*)p;  p += NWB;
  bf16* wvb = (bf16*)p;  p += NWB;
  bf16* wfcb = (bf16*)p; p += NWB;
  bf16* Qb = (bf16*)p;   p += NBIG;
  bf16* Kb = (bf16*)p;   p += NBIG;
  bf16* Vb = (bf16*)p;   p += NBIG;
  bf16* Vtb = (bf16*)p;  p += NBIG;
  bf16* Ob = (bf16*)p;   p += NBIG;

  const float c1 = 0.125f * 1.44269504088896340736f;  // softmax scale * log2(e)

  const long total4 = ((long)S_LEN * HID + 4L * HID * HID) / 4;
  cvt_all<<<(int)(total4 / 256), 256, 0, stream>>>(x, wq, wk, wv, wfc, xb, wqb, wkb,
                                                   wvb, wfcb);
  gemm_bt<bf16><<<dim3(HID / 128, S_LEN / 128, 3), 256, 0, stream>>>(
      xb, wqb, wkb, wvb, Qb, Kb, Vb, c1);
  transpose_v<<<dim3(S_LEN / 64, HID / 64), 256, 0, stream>>>(Vb, Vtb);
  flash_attn<<<dim3(S_LEN / QB * NHEAD), 256, 0, stream>>>(Qb, Kb, Vtb, Ob);
  gemm_fc<<<dim3(HID / 64, S_LEN / 128), 256, 0, stream>>>(Ob, wfcb, out);
}

// Round 7
// 254.515 us; speedup vs baseline: 1.0895x; 1.0895x over previous
//
#include <hip/hip_runtime.h>
#include <hip/hip_bf16.h>

#define S_LEN 4096
#define HID 768
#define NHEAD 12
#define HL 64
#define QB 64   // q rows per block: 768 blocks, 3 blocks/CU
#define ORST 68 // O-reduction LDS row stride (64 + 4 pad): 2-way banks (free)

typedef __attribute__((ext_vector_type(8))) short short8;
typedef __attribute__((ext_vector_type(4))) short s16x4;
typedef __attribute__((ext_vector_type(4))) float f32x4;
using bf16 = __hip_bfloat16;

__device__ __forceinline__ void gl2lds16(const void* g, void* l) {
  __builtin_amdgcn_global_load_lds((__attribute__((address_space(1))) void*)(g),
                                   (__attribute__((address_space(3))) void*)(l),
                                   16, 0, 0);
}

__device__ __forceinline__ f32x4 mfma_bf16(short8 a, short8 b, f32x4 c) {
  return __builtin_amdgcn_mfma_f32_16x16x32_bf16(a, b, c, 0, 0, 0);
}

// K=16 bf16 MFMA (carried-forward gfx90a builtin; instruction in gfx950 ISA).
__device__ __forceinline__ f32x4 mfma16_bf16(s16x4 a, s16x4 b, f32x4 c) {
#if __has_builtin(__builtin_amdgcn_mfma_f32_16x16x16bf16_1k)
  return __builtin_amdgcn_mfma_f32_16x16x16bf16_1k(a, b, c, 0, 0, 0);
#elif __has_builtin(__builtin_amdgcn_mfma_f32_16x16x16_bf16)
  return __builtin_amdgcn_mfma_f32_16x16x16_bf16(a, b, c, 0, 0, 0);
#else
  f32x4 d;
  asm volatile(
      "s_nop 1\n\t"
      "v_mfma_f32_16x16x16_bf16 %0, %1, %2, %3\n\t"
      "s_nop 7\n\t"
      "s_nop 2"
      : "=&v"(d)
      : "v"(a), "v"(b), "v"(c));
  return d;
#endif
}

__device__ __forceinline__ void storeC(float* C, long idx, float v) { C[idx] = v; }
__device__ __forceinline__ void storeC(bf16* C, long idx, float v) { C[idx] = __float2bfloat16(v); }

// ---------------- fp32 -> bf16 convert (x + 4 weights, fused) ----------------
__global__ __launch_bounds__(256) void cvt_all(
    const float* __restrict__ x, const float* __restrict__ wq,
    const float* __restrict__ wk, const float* __restrict__ wv,
    const float* __restrict__ wfc, bf16* __restrict__ xb, bf16* __restrict__ wqb,
    bf16* __restrict__ wkb, bf16* __restrict__ wvb, bf16* __restrict__ wfcb) {
  const long NX = (long)S_LEN * HID;
  const long NW = (long)HID * HID;
  long i = ((long)blockIdx.x * 256 + threadIdx.x) * 4;
  const float* src;
  bf16* dst;
  long off;
  if (i < NX) {
    src = x; dst = xb; off = i;
  } else {
    long j = i - NX;
    int wsel = (int)(j / NW);
    off = j - (long)wsel * NW;
    src = wsel == 0 ? wq : wsel == 1 ? wk : wsel == 2 ? wv : wfc;
    dst = wsel == 0 ? wqb : wsel == 1 ? wkb : wsel == 2 ? wvb : wfcb;
  }
  float4 v = *(const float4*)(src + off);
  bf16 h0 = __float2bfloat16(v.x), h1 = __float2bfloat16(v.y);
  bf16 h2 = __float2bfloat16(v.z), h3 = __float2bfloat16(v.w);
  ushort4 o;
  o.x = *(unsigned short*)&h0; o.y = *(unsigned short*)&h1;
  o.z = *(unsigned short*)&h2; o.w = *(unsigned short*)&h3;
  *(ushort4*)(dst + off) = o;
}

// ---------------- GEMM: C[M x 768] = scale * A[M x 768] * B[768 x 768]^T ------
template <typename OT>
__global__ __launch_bounds__(256) void gemm_bt(
    const bf16* __restrict__ A, const bf16* __restrict__ B0,
    const bf16* __restrict__ B1, const bf16* __restrict__ B2,
    OT* __restrict__ C0, OT* __restrict__ C1, OT* __restrict__ C2, float qscale) {
  constexpr int K = HID;
  __shared__ __align__(16) bf16 As[128 * 32];
  __shared__ __align__(16) bf16 Bs[128 * 32];
  const int z = blockIdx.z;
  const bf16* B = (z == 0) ? B0 : (z == 1) ? B1 : B2;
  OT* C = (z == 0) ? C0 : (z == 1) ? C1 : C2;
  const float sc = (z == 0) ? qscale : 1.0f;
  const int bm = blockIdx.y, bn = blockIdx.x;
  const int t = threadIdx.x, lane = t & 63, w = t >> 6;
  const int wm = w >> 1, wn = w & 1;
  const int q4 = lane >> 4, c16 = lane & 15;
  const int srow = lane >> 2, scol = (lane & 3) * 8;
  const bf16* Ab = A + (long)bm * 128 * K;
  const bf16* Bb = B + (long)bn * 128 * K;
  f32x4 acc[4][4] = {};
  for (int k0 = 0; k0 < K; k0 += 32) {
#pragma unroll
    for (int r = 0; r < 2; ++r) {
      int rowb = r * 64 + w * 16;
      gl2lds16(Ab + (long)(rowb + srow) * K + k0 + scol, &As[rowb * 32]);
      gl2lds16(Bb + (long)(rowb + srow) * K + k0 + scol, &Bs[rowb * 32]);
    }
    __syncthreads();
    short8 af[4], bfv[4];
#pragma unroll
    for (int i = 0; i < 4; ++i)
      af[i] = *(const short8*)&As[(wm * 64 + i * 16 + c16) * 32 + q4 * 8];
#pragma unroll
    for (int j = 0; j < 4; ++j)
      bfv[j] = *(const short8*)&Bs[(wn * 64 + j * 16 + c16) * 32 + q4 * 8];
#pragma unroll
    for (int i = 0; i < 4; ++i)
#pragma unroll
      for (int j = 0; j < 4; ++j)
        acc[i][j] = mfma_bf16(af[i], bfv[j], acc[i][j]);
    __syncthreads();
  }
  const long crow0 = (long)bm * 128 + wm * 64;
  const int ccol0 = bn * 128 + wn * 64;
#pragma unroll
  for (int i = 0; i < 4; ++i)
#pragma unroll
    for (int j = 0; j < 4; ++j)
#pragma unroll
      for (int r = 0; r < 4; ++r) {
        long row = crow0 + i * 16 + q4 * 4 + r;
        int col = ccol0 + j * 16 + c16;
        storeC(C, row * HID + col, sc * acc[i][j][r]);
      }
}

// ---------------- final GEMM: 128x64 tile (384 blocks, better occupancy) ------
__global__ __launch_bounds__(256) void gemm_fc(const bf16* __restrict__ A,
                                               const bf16* __restrict__ B,
                                               float* __restrict__ C) {
  __shared__ __align__(16) bf16 As[128 * 32];
  __shared__ __align__(16) bf16 Bs[64 * 32];
  const int bm = blockIdx.y, bn = blockIdx.x;
  const int t = threadIdx.x, lane = t & 63, w = t >> 6;
  const int q4 = lane >> 4, c16 = lane & 15;
  const int srow = lane >> 2, scol = (lane & 3) * 8;
  const bf16* Ab = A + (long)bm * 128 * HID;
  const bf16* Bb = B + (long)bn * 64 * HID;
  f32x4 acc[2][4] = {};
  for (int k0 = 0; k0 < HID; k0 += 32) {
#pragma unroll
    for (int r = 0; r < 2; ++r) {
      int rowb = w * 32 + r * 16;
      gl2lds16(Ab + (long)(rowb + srow) * HID + k0 + scol, &As[rowb * 32]);
    }
    gl2lds16(Bb + (long)(w * 16 + srow) * HID + k0 + scol, &Bs[w * 16 * 32]);
    __syncthreads();
    short8 af[2], bfv[4];
#pragma unroll
    for (int i = 0; i < 2; ++i)
      af[i] = *(const short8*)&As[(w * 32 + i * 16 + c16) * 32 + q4 * 8];
#pragma unroll
    for (int j = 0; j < 4; ++j)
      bfv[j] = *(const short8*)&Bs[(j * 16 + c16) * 32 + q4 * 8];
#pragma unroll
    for (int i = 0; i < 2; ++i)
#pragma unroll
      for (int j = 0; j < 4; ++j)
        acc[i][j] = mfma_bf16(af[i], bfv[j], acc[i][j]);
    __syncthreads();
  }
#pragma unroll
  for (int i = 0; i < 2; ++i)
#pragma unroll
    for (int j = 0; j < 4; ++j)
#pragma unroll
      for (int r = 0; r < 4; ++r) {
        long row = (long)bm * 128 + w * 32 + i * 16 + q4 * 4 + r;
        int col = bn * 64 + j * 16 + c16;
        C[row * HID + col] = acc[i][j][r];
      }
}

// ---------------- V transpose: [4096][768] -> [768][4096] ----------------
__global__ __launch_bounds__(256) void transpose_v(const bf16* __restrict__ V,
                                                   bf16* __restrict__ Vt) {
  __shared__ unsigned short tile[64][65];
  const int bs = blockIdx.x * 64;
  const int be = blockIdx.y * 64;
  const int t = threadIdx.x;
#pragma unroll
  for (int p = 0; p < 4; ++p) {
    int i = p * 256 + t;
    int r = i >> 4;
    int c = (i & 15) * 4;
    ushort4 v = *(const ushort4*)((const unsigned short*)V + (long)(bs + r) * HID + be + c);
    tile[r][c] = v.x; tile[r][c + 1] = v.y; tile[r][c + 2] = v.z; tile[r][c + 3] = v.w;
  }
  __syncthreads();
#pragma unroll
  for (int p = 0; p < 4; ++p) {
    int i = p * 256 + t;
    int r = i >> 4;
    int c = (i & 15) * 4;
    ushort4 v;
    v.x = tile[c][r]; v.y = tile[c + 1][r]; v.z = tile[c + 2][r]; v.w = tile[c + 3][r];
    *(ushort4*)((unsigned short*)Vt + (long)(be + r) * S_LEN + bs + c) = v;
  }
}

// ---------------- flash attention v9: v8 + fully-static o_acc indexing --------
// v8 proved the register-direct P mechanism (bank conflicts 9.4M -> 0) but
// REGRESSED to 171us: the epilogue's `#pragma unroll 1` rd-loop indexed
// o_acc[rd] at runtime -> compiler allocated the whole 64-VGPR accumulator in
// SCRATCH (VGPR_Count 76, WRITE_SIZE 6MB -> 110MB = the smoking gun; every
// main-loop MFMA round-tripped C/D through global memory). v9: fully unroll
// the rd loop so ALL o_acc accesses are compile-time-static -> o_acc stays in
// VGPRs. Main loop unchanged: 24 MFMA + ~120 VALU + 6 vmem, 0 LDS ops,
// 0 barriers per wave-iter. XCD swizzle kept (K/V L2-local).
__global__ __launch_bounds__(256, 3) void flash_attn(const bf16* __restrict__ Q,
                                                     const bf16* __restrict__ Kg,
                                                     const bf16* __restrict__ Vt,
                                                     bf16* __restrict__ O) {
  __shared__ float Ored[64 * ORST];  // [w*16 + d'][q], 17.4 KB
  __shared__ float Lred[4][QB];
  const int i0 = blockIdx.x;
  const int xcd = i0 & 7, sb = i0 >> 3;
  const int pair = xcd >> 1;
  const int r2 = sb * 2 + (xcd & 1);
  const int h = pair * 3 + (r2 >> 6);
  const int qt = r2 & 63;
  const int t = threadIdx.x, lane = t & 63, w = t >> 6;
  const int q4 = lane >> 4, c16 = lane & 15;
  const int s0 = qt * QB;

  // Q B-frags, loop-invariant: row q = s0 + j*16 + c16, k-chunk = ks*32 + q4*8
  short8 qf[2][4];
  {
    const bf16* Qb = Q + (long)(s0 + c16) * HID + h * HL + q4 * 8;
#pragma unroll
    for (int j = 0; j < 4; ++j)
#pragma unroll
      for (int ks = 0; ks < 2; ++ks)
        qf[ks][j] = *(const short8*)(Qb + (long)j * 16 * HID + ks * 32);
  }
  // K A-frag base: row kv = kt*64 + w*16 + c16, k-chunk = ks*32 + q4*8
  const bf16* kp = Kg + (long)(w * 16 + c16) * HID + h * HL + q4 * 8;
  // V^T K=16 A-frag base: row d = i*16 + c16, k = kt*64 + w*16 + q4*4 + e
  const bf16* vbase = Vt + (long)(h * HL + c16) * S_LEN + w * 16 + q4 * 4;

  float l_part[4] = {0.f, 0.f, 0.f, 0.f};
  f32x4 o_acc[4][4] = {};  // [i = d-tile][j = q-tile], O^T partial (wave's kv)

  short8 kf0 = *(const short8*)(kp), kf1 = *(const short8*)(kp + 32);

  constexpr int NT = S_LEN / 64;
  for (int kt = 0; kt < NT; ++kt) {
    // ---- prefetch next K tile (consumed at next iter top) ----
    const bf16* kpn = (kt + 1 < NT) ? kp + 64 * HID : kp;
    short8 nk0 = *(const short8*)(kpn), nk1 = *(const short8*)(kpn + 32);
    // ---- current V^T frags (consumed after QK+exp: in-iter latency slack) ----
    s16x4 vf[4];
#pragma unroll
    for (int i = 0; i < 4; ++i)
      vf[i] = *(const s16x4*)(vbase + (long)i * 16 * S_LEN + kt * 64);

    // ---- S^T = K . Q^T : D[kv(wave's 16)][q 64] ----
    f32x4 sacc[4] = {};
#pragma unroll
    for (int j = 0; j < 4; ++j) sacc[j] = mfma_bf16(kf0, qf[0][j], sacc[j]);
#pragma unroll
    for (int j = 0; j < 4; ++j) sacc[j] = mfma_bf16(kf1, qf[1][j], sacc[j]);

    // ---- per q-tile: exp2 -> pack (IS the K=16 B-frag) -> PV, all in regs ----
#pragma unroll
    for (int j = 0; j < 4; ++j) {
      float p0 = __builtin_amdgcn_exp2f(sacc[j][0]);
      float p1 = __builtin_amdgcn_exp2f(sacc[j][1]);
      float p2 = __builtin_amdgcn_exp2f(sacc[j][2]);
      float p3 = __builtin_amdgcn_exp2f(sacc[j][3]);
      l_part[j] += (p0 + p1) + (p2 + p3);
      bf16 b0 = __float2bfloat16(p0), b1 = __float2bfloat16(p1);
      bf16 b2 = __float2bfloat16(p2), b3 = __float2bfloat16(p3);
      s16x4 pf;
      pf[0] = *(short*)&b0; pf[1] = *(short*)&b1;
      pf[2] = *(short*)&b2; pf[3] = *(short*)&b3;
      // O^T[d = i*16 + q4*4 + r][q = j*16 + c16] += V^T . P^T (K = wave's 16 kv)
#pragma unroll
      for (int i = 0; i < 4; ++i)
        o_acc[i][j] = mfma16_bf16(vf[i], pf, o_acc[i][j]);
    }

    kf0 = nk0; kf1 = nk1; kp = kpn;
  }

  // ---- l reduction: quad-sum (kv within wave) then cross-wave via LDS ----
#pragma unroll
  for (int j = 0; j < 4; ++j) {
    float s = l_part[j];
    s += __shfl_xor(s, 16, 64);
    s += __shfl_xor(s, 32, 64);
    Lred[w][j * 16 + c16] = s;  // all quads write same value: benign
  }
  __syncthreads();
  float rl[4];
#pragma unroll
  for (int j = 0; j < 4; ++j) {
    int q = j * 16 + c16;
    rl[j] = 1.0f / (Lred[0][q] + Lred[1][q] + Lred[2][q] + Lred[3][q]);
  }

  // ---- O^T cross-wave reduction: 4 rounds, FULLY UNROLLED (rd static so
  // o_acc stays in VGPRs - rule #20); round rd reduces d-tile rd, owned by
  // wave rd (normalize + pack + store). Banks: 2 lanes/bank (free). ----
#pragma unroll
  for (int rd = 0; rd < 4; ++rd) {
#pragma unroll
    for (int j = 0; j < 4; ++j)
#pragma unroll
      for (int r = 0; r < 4; ++r)
        Ored[(w * 16 + q4 * 4 + r) * ORST + j * 16 + c16] = o_acc[rd][j][r];
    __syncthreads();
    if (w == rd) {
#pragma unroll
      for (int j = 0; j < 4; ++j) {
        float v[4];
#pragma unroll
        for (int r = 0; r < 4; ++r) {
          int off = (q4 * 4 + r) * ORST + j * 16 + c16;
          v[r] = (Ored[off] + Ored[16 * ORST + off]) +
                 (Ored[32 * ORST + off] + Ored[48 * ORST + off]);
          v[r] *= rl[j];
        }
        bf16 b0 = __float2bfloat16(v[0]), b1 = __float2bfloat16(v[1]);
        bf16 b2 = __float2bfloat16(v[2]), b3 = __float2bfloat16(v[3]);
        short4 pk;
        pk.x = *(short*)&b0; pk.y = *(short*)&b1;
        pk.z = *(short*)&b2; pk.w = *(short*)&b3;
        // O[s0 + q][h*64 + d], d = rd*16 + q4*4 + r
        *(short4*)&O[(long)(s0 + j * 16 + c16) * HID + h * HL + rd * 16 + q4 * 4] = pk;
      }
    }
    __syncthreads();
  }
}

extern "C" void kernel_launch(void* const* d_in, const int* in_sizes, int n_in,
                              void* d_out, int out_size, void* d_ws, size_t ws_size,
                              hipStream_t stream) {
  const float* x = (const float*)d_in[0];
  const float* wq = (const float*)d_in[1];
  const float* wk = (const float*)d_in[2];
  const float* wv = (const float*)d_in[3];
  const float* wfc = (const float*)d_in[4];
  float* out = (float*)d_out;

  const long NBIG = (long)S_LEN * HID * sizeof(bf16);
  const long NWB = (long)HID * HID * sizeof(bf16);
  char* p = (char*)d_ws;
  bf16* xb = (bf16*)p;   p += NBIG;
  bf16* wqb = (bf16*)p;  p += NWB;
  bf16* wkb = (bf16*)p;  p += NWB;
  bf16* wvb = (bf16*)p;  p += NWB;
  bf16* wfcb = (bf16*)p; p += NWB;
  bf16* Qb = (bf16*)p;   p += NBIG;
  bf16* Kb = (bf16*)p;   p += NBIG;
  bf16* Vb = (bf16*)p;   p += NBIG;
  bf16* Vtb = (bf16*)p;  p += NBIG;
  bf16* Ob = (bf16*)p;   p += NBIG;

  const float c1 = 0.125f * 1.44269504088896340736f;  // softmax scale * log2(e)

  const long total4 = ((long)S_LEN * HID + 4L * HID * HID) / 4;
  cvt_all<<<(int)(total4 / 256), 256, 0, stream>>>(x, wq, wk, wv, wfc, xb, wqb, wkb,
                                                   wvb, wfcb);
  gemm_bt<bf16><<<dim3(HID / 128, S_LEN / 128, 3), 256, 0, stream>>>(
      xb, wqb, wkb, wvb, Qb, Kb, Vb, c1);
  transpose_v<<<dim3(S_LEN / 64, HID / 64), 256, 0, stream>>>(Vb, Vtb);
  flash_attn<<<dim3(S_LEN / QB * NHEAD), 256, 0, stream>>>(Qb, Kb, Vtb, Ob);
  gemm_fc<<<dim3(HID / 64, S_LEN / 128), 256, 0, stream>>>(Ob, wfcb, out);
}

// Round 8
// 254.031 us; speedup vs baseline: 1.0915x; 1.0019x over previous
//
#include <hip/hip_runtime.h>
#include <hip/hip_bf16.h>

#define S_LEN 4096
#define HID 768
#define NHEAD 12
#define HL 64
#define QB 64   // q rows per block: 768 blocks, 3 blocks/CU
#define ORST 68 // O-reduction LDS row stride (64 + 4 pad): 2-way banks (free)

typedef __attribute__((ext_vector_type(8))) short short8;
typedef __attribute__((ext_vector_type(4))) short s16x4;
typedef __attribute__((ext_vector_type(4))) float f32x4;
using bf16 = __hip_bfloat16;

__device__ __forceinline__ void gl2lds16(const void* g, void* l) {
  __builtin_amdgcn_global_load_lds((__attribute__((address_space(1))) void*)(g),
                                   (__attribute__((address_space(3))) void*)(l),
                                   16, 0, 0);
}

__device__ __forceinline__ f32x4 mfma_bf16(short8 a, short8 b, f32x4 c) {
  return __builtin_amdgcn_mfma_f32_16x16x32_bf16(a, b, c, 0, 0, 0);
}

// K=16 bf16 MFMA (carried-forward gfx90a builtin; instruction in gfx950 ISA).
__device__ __forceinline__ f32x4 mfma16_bf16(s16x4 a, s16x4 b, f32x4 c) {
#if __has_builtin(__builtin_amdgcn_mfma_f32_16x16x16bf16_1k)
  return __builtin_amdgcn_mfma_f32_16x16x16bf16_1k(a, b, c, 0, 0, 0);
#elif __has_builtin(__builtin_amdgcn_mfma_f32_16x16x16_bf16)
  return __builtin_amdgcn_mfma_f32_16x16x16_bf16(a, b, c, 0, 0, 0);
#else
  f32x4 d;
  asm volatile(
      "s_nop 1\n\t"
      "v_mfma_f32_16x16x16_bf16 %0, %1, %2, %3\n\t"
      "s_nop 7\n\t"
      "s_nop 2"
      : "=&v"(d)
      : "v"(a), "v"(b), "v"(c));
  return d;
#endif
}

__device__ __forceinline__ void storeC(float* C, long idx, float v) { C[idx] = v; }
__device__ __forceinline__ void storeC(bf16* C, long idx, float v) { C[idx] = __float2bfloat16(v); }

// ---------------- fp32 -> bf16 convert (x + 4 weights, fused) ----------------
__global__ __launch_bounds__(256) void cvt_all(
    const float* __restrict__ x, const float* __restrict__ wq,
    const float* __restrict__ wk, const float* __restrict__ wv,
    const float* __restrict__ wfc, bf16* __restrict__ xb, bf16* __restrict__ wqb,
    bf16* __restrict__ wkb, bf16* __restrict__ wvb, bf16* __restrict__ wfcb) {
  const long NX = (long)S_LEN * HID;
  const long NW = (long)HID * HID;
  long i = ((long)blockIdx.x * 256 + threadIdx.x) * 4;
  const float* src;
  bf16* dst;
  long off;
  if (i < NX) {
    src = x; dst = xb; off = i;
  } else {
    long j = i - NX;
    int wsel = (int)(j / NW);
    off = j - (long)wsel * NW;
    src = wsel == 0 ? wq : wsel == 1 ? wk : wsel == 2 ? wv : wfc;
    dst = wsel == 0 ? wqb : wsel == 1 ? wkb : wsel == 2 ? wvb : wfcb;
  }
  float4 v = *(const float4*)(src + off);
  bf16 h0 = __float2bfloat16(v.x), h1 = __float2bfloat16(v.y);
  bf16 h2 = __float2bfloat16(v.z), h3 = __float2bfloat16(v.w);
  ushort4 o;
  o.x = *(unsigned short*)&h0; o.y = *(unsigned short*)&h1;
  o.z = *(unsigned short*)&h2; o.w = *(unsigned short*)&h3;
  *(ushort4*)(dst + off) = o;
}

// ---------------- GEMM: C[M x 768] = scale * A[M x 768] * B[768 x 768]^T ------
template <typename OT>
__global__ __launch_bounds__(256) void gemm_bt(
    const bf16* __restrict__ A, const bf16* __restrict__ B0,
    const bf16* __restrict__ B1, const bf16* __restrict__ B2,
    OT* __restrict__ C0, OT* __restrict__ C1, OT* __restrict__ C2, float qscale) {
  constexpr int K = HID;
  __shared__ __align__(16) bf16 As[128 * 32];
  __shared__ __align__(16) bf16 Bs[128 * 32];
  const int z = blockIdx.z;
  const bf16* B = (z == 0) ? B0 : (z == 1) ? B1 : B2;
  OT* C = (z == 0) ? C0 : (z == 1) ? C1 : C2;
  const float sc = (z == 0) ? qscale : 1.0f;
  const int bm = blockIdx.y, bn = blockIdx.x;
  const int t = threadIdx.x, lane = t & 63, w = t >> 6;
  const int wm = w >> 1, wn = w & 1;
  const int q4 = lane >> 4, c16 = lane & 15;
  const int srow = lane >> 2, scol = (lane & 3) * 8;
  const bf16* Ab = A + (long)bm * 128 * K;
  const bf16* Bb = B + (long)bn * 128 * K;
  f32x4 acc[4][4] = {};
  for (int k0 = 0; k0 < K; k0 += 32) {
#pragma unroll
    for (int r = 0; r < 2; ++r) {
      int rowb = r * 64 + w * 16;
      gl2lds16(Ab + (long)(rowb + srow) * K + k0 + scol, &As[rowb * 32]);
      gl2lds16(Bb + (long)(rowb + srow) * K + k0 + scol, &Bs[rowb * 32]);
    }
    __syncthreads();
    short8 af[4], bfv[4];
#pragma unroll
    for (int i = 0; i < 4; ++i)
      af[i] = *(const short8*)&As[(wm * 64 + i * 16 + c16) * 32 + q4 * 8];
#pragma unroll
    for (int j = 0; j < 4; ++j)
      bfv[j] = *(const short8*)&Bs[(wn * 64 + j * 16 + c16) * 32 + q4 * 8];
#pragma unroll
    for (int i = 0; i < 4; ++i)
#pragma unroll
      for (int j = 0; j < 4; ++j)
        acc[i][j] = mfma_bf16(af[i], bfv[j], acc[i][j]);
    __syncthreads();
  }
  const long crow0 = (long)bm * 128 + wm * 64;
  const int ccol0 = bn * 128 + wn * 64;
#pragma unroll
  for (int i = 0; i < 4; ++i)
#pragma unroll
    for (int j = 0; j < 4; ++j)
#pragma unroll
      for (int r = 0; r < 4; ++r) {
        long row = crow0 + i * 16 + q4 * 4 + r;
        int col = ccol0 + j * 16 + c16;
        storeC(C, row * HID + col, sc * acc[i][j][r]);
      }
}

// ---------------- final GEMM: 128x64 tile (384 blocks, better occupancy) ------
__global__ __launch_bounds__(256) void gemm_fc(const bf16* __restrict__ A,
                                               const bf16* __restrict__ B,
                                               float* __restrict__ C) {
  __shared__ __align__(16) bf16 As[128 * 32];
  __shared__ __align__(16) bf16 Bs[64 * 32];
  const int bm = blockIdx.y, bn = blockIdx.x;
  const int t = threadIdx.x, lane = t & 63, w = t >> 6;
  const int q4 = lane >> 4, c16 = lane & 15;
  const int srow = lane >> 2, scol = (lane & 3) * 8;
  const bf16* Ab = A + (long)bm * 128 * HID;
  const bf16* Bb = B + (long)bn * 64 * HID;
  f32x4 acc[2][4] = {};
  for (int k0 = 0; k0 < HID; k0 += 32) {
#pragma unroll
    for (int r = 0; r < 2; ++r) {
      int rowb = w * 32 + r * 16;
      gl2lds16(Ab + (long)(rowb + srow) * HID + k0 + scol, &As[rowb * 32]);
    }
    gl2lds16(Bb + (long)(w * 16 + srow) * HID + k0 + scol, &Bs[w * 16 * 32]);
    __syncthreads();
    short8 af[2], bfv[4];
#pragma unroll
    for (int i = 0; i < 2; ++i)
      af[i] = *(const short8*)&As[(w * 32 + i * 16 + c16) * 32 + q4 * 8];
#pragma unroll
    for (int j = 0; j < 4; ++j)
      bfv[j] = *(const short8*)&Bs[(j * 16 + c16) * 32 + q4 * 8];
#pragma unroll
    for (int i = 0; i < 2; ++i)
#pragma unroll
      for (int j = 0; j < 4; ++j)
        acc[i][j] = mfma_bf16(af[i], bfv[j], acc[i][j]);
    __syncthreads();
  }
#pragma unroll
  for (int i = 0; i < 2; ++i)
#pragma unroll
    for (int j = 0; j < 4; ++j)
#pragma unroll
      for (int r = 0; r < 4; ++r) {
        long row = (long)bm * 128 + w * 32 + i * 16 + q4 * 4 + r;
        int col = bn * 64 + j * 16 + c16;
        C[row * HID + col] = acc[i][j][r];
      }
}

// ---------------- V transpose: [4096][768] -> [768][4096] ----------------
__global__ __launch_bounds__(256) void transpose_v(const bf16* __restrict__ V,
                                                   bf16* __restrict__ Vt) {
  __shared__ unsigned short tile[64][65];
  const int bs = blockIdx.x * 64;
  const int be = blockIdx.y * 64;
  const int t = threadIdx.x;
#pragma unroll
  for (int p = 0; p < 4; ++p) {
    int i = p * 256 + t;
    int r = i >> 4;
    int c = (i & 15) * 4;
    ushort4 v = *(const ushort4*)((const unsigned short*)V + (long)(bs + r) * HID + be + c);
    tile[r][c] = v.x; tile[r][c + 1] = v.y; tile[r][c + 2] = v.z; tile[r][c + 3] = v.w;
  }
  __syncthreads();
#pragma unroll
  for (int p = 0; p < 4; ++p) {
    int i = p * 256 + t;
    int r = i >> 4;
    int c = (i & 15) * 4;
    ushort4 v;
    v.x = tile[c][r]; v.y = tile[c + 1][r]; v.z = tile[c + 2][r]; v.w = tile[c + 3][r];
    *(ushort4*)((unsigned short*)Vt + (long)(be + r) * S_LEN + bs + c) = v;
  }
}

// ---------------- flash attention v10: register pipeline (PV(t) || QK(t+1)) ---
// v9 (register-direct, 0 conflicts, 0 barriers) = 146us, WORSE than v5's
// LDS-pipelined 104us: v9's iteration is one serial chain QK->exp->PV with
// only 3 waves/SIMD to cover the latencies. v10 restores v5's cross-iteration
// overlap IN REGISTERS: P double-buffered (pfA/pfB, 8 VGPR each); per body:
//   QK(t+1) [mfma]  ->  kf <- K(t+2) (overwrite after last use; no extra regs)
//   PV(t) from pfA  [mfma, independent of this body's QK/exp]
//   vf <- V(t+1)    [8B loads, in flight until next body's PV]
//   exp(t+1) -> pfB [VALU, overlaps PV execution]
// Every consumer is >=1 body (~500cyc) after its producer's issue. All MFMAs
// via builtins (compiler handles hazards); all array indexing static
// (_Pragma macro with named pfA/pfB - rule #20). ~156 VGPR -> 3 blocks/CU.
// XCD swizzle kept (K/V L2-local, FETCH 15MB).
__global__ __launch_bounds__(256, 3) void flash_attn(const bf16* __restrict__ Q,
                                                     const bf16* __restrict__ Kg,
                                                     const bf16* __restrict__ Vt,
                                                     bf16* __restrict__ O) {
  __shared__ float Ored[64 * ORST];  // [w*16 + d'][q], 17.4 KB
  __shared__ float Lred[4][QB];
  const int i0 = blockIdx.x;
  const int xcd = i0 & 7, sb = i0 >> 3;
  const int pair = xcd >> 1;
  const int r2 = sb * 2 + (xcd & 1);
  const int h = pair * 3 + (r2 >> 6);
  const int qt = r2 & 63;
  const int t = threadIdx.x, lane = t & 63, w = t >> 6;
  const int q4 = lane >> 4, c16 = lane & 15;
  const int s0 = qt * QB;
  constexpr int NT = S_LEN / 64;

  // Q B-frags, loop-invariant: row q = s0 + j*16 + c16, k-chunk = ks*32 + q4*8
  short8 qf[2][4];
  {
    const bf16* Qb = Q + (long)(s0 + c16) * HID + h * HL + q4 * 8;
#pragma unroll
    for (int j = 0; j < 4; ++j)
#pragma unroll
      for (int ks = 0; ks < 2; ++ks)
        qf[ks][j] = *(const short8*)(Qb + (long)j * 16 * HID + ks * 32);
  }
  // K A-frag base: row kv = kt*64 + w*16 + c16, k-chunk = ks*32 + q4*8
  const bf16* kp = Kg + (long)(w * 16 + c16) * HID + h * HL + q4 * 8;
  // V^T K=16 A-frag base: row d = i*16 + c16, k = kt*64 + w*16 + q4*4 + e
  const bf16* vbase = Vt + (long)(h * HL + c16) * S_LEN + w * 16 + q4 * 4;

  float l_part[4] = {0.f, 0.f, 0.f, 0.f};
  f32x4 o_acc[4][4] = {};  // [i = d-tile][j = q-tile], O^T partial (wave's kv)
  s16x4 pfA[4], pfB[4];    // packed P (K=16 B-frags), double-buffered
  s16x4 vf[4];             // V^T A-frags for the PV of the current body
  short8 kf0, kf1;

  // ---- prologue: QK(0)+exp -> pfA; kf <- K(1); vf <- V(0) ----
  kf0 = *(const short8*)kp;
  kf1 = *(const short8*)(kp + 32);
  {
    f32x4 sacc[4] = {};
#pragma unroll
    for (int j = 0; j < 4; ++j) sacc[j] = mfma_bf16(kf0, qf[0][j], sacc[j]);
#pragma unroll
    for (int j = 0; j < 4; ++j) sacc[j] = mfma_bf16(kf1, qf[1][j], sacc[j]);
#pragma unroll
    for (int j = 0; j < 4; ++j) {
      float p0 = __builtin_amdgcn_exp2f(sacc[j][0]);
      float p1 = __builtin_amdgcn_exp2f(sacc[j][1]);
      float p2 = __builtin_amdgcn_exp2f(sacc[j][2]);
      float p3 = __builtin_amdgcn_exp2f(sacc[j][3]);
      l_part[j] += (p0 + p1) + (p2 + p3);
      bf16 b0 = __float2bfloat16(p0), b1 = __float2bfloat16(p1);
      bf16 b2 = __float2bfloat16(p2), b3 = __float2bfloat16(p3);
      pfA[j][0] = *(short*)&b0; pfA[j][1] = *(short*)&b1;
      pfA[j][2] = *(short*)&b2; pfA[j][3] = *(short*)&b3;
    }
  }
  kp += 64 * HID;
  kf0 = *(const short8*)kp;
  kf1 = *(const short8*)(kp + 32);
#pragma unroll
  for (int i = 0; i < 4; ++i)
    vf[i] = *(const s16x4*)(vbase + (long)i * 16 * S_LEN);

// Body T: QK(T+1) with kf; kf<-K(T+2); PV(T) from PFU+vf; vf<-V(T+1);
// exp(T+1)->PFM.  (PFU/PFM are the literal names pfA/pfB -> static indexing.)
#define FA_BODY(T, PFU, PFM)                                                   \
  {                                                                            \
    f32x4 sacc[4] = {};                                                        \
    _Pragma("unroll") for (int j = 0; j < 4; ++j)                              \
        sacc[j] = mfma_bf16(kf0, qf[0][j], sacc[j]);                           \
    _Pragma("unroll") for (int j = 0; j < 4; ++j)                              \
        sacc[j] = mfma_bf16(kf1, qf[1][j], sacc[j]);                           \
    const bf16* kpn_ = ((T) + 2 < NT) ? kp + 64 * HID : kp;                    \
    kf0 = *(const short8*)(kpn_);                                              \
    kf1 = *(const short8*)(kpn_ + 32);                                         \
    kp = kpn_;                                                                 \
    _Pragma("unroll") for (int j = 0; j < 4; ++j)                              \
        _Pragma("unroll") for (int i = 0; i < 4; ++i)                          \
            o_acc[i][j] = mfma16_bf16(vf[i], PFU[j], o_acc[i][j]);             \
    const bf16* vpn_ = vbase + (long)(((T) + 1 < NT) ? (T) + 1 : (T)) * 64;    \
    _Pragma("unroll") for (int i = 0; i < 4; ++i)                              \
        vf[i] = *(const s16x4*)(vpn_ + (long)i * 16 * S_LEN);                  \
    _Pragma("unroll") for (int j = 0; j < 4; ++j) {                            \
      float p0 = __builtin_amdgcn_exp2f(sacc[j][0]);                           \
      float p1 = __builtin_amdgcn_exp2f(sacc[j][1]);                           \
      float p2 = __builtin_amdgcn_exp2f(sacc[j][2]);                           \
      float p3 = __builtin_amdgcn_exp2f(sacc[j][3]);                           \
      l_part[j] += (p0 + p1) + (p2 + p3);                                      \
      bf16 b0 = __float2bfloat16(p0), b1 = __float2bfloat16(p1);               \
      bf16 b2 = __float2bfloat16(p2), b3 = __float2bfloat16(p3);               \
      PFM[j][0] = *(short*)&b0; PFM[j][1] = *(short*)&b1;                      \
      PFM[j][2] = *(short*)&b2; PFM[j][3] = *(short*)&b3;                      \
    }                                                                          \
  }

  // bodies T=0..62 (odd count): 31 pairs + 1; even bodies consume pfA,
  // odd consume pfB. Body 62 produces pfB = P(63); vf ends as V(63).
  for (int T = 0; T < 62; T += 2) {
    FA_BODY(T, pfA, pfB);
    FA_BODY(T + 1, pfB, pfA);
  }
  FA_BODY(62, pfA, pfB);
#undef FA_BODY

  // ---- epilogue: PV(63) from pfB, vf = V(63) ----
#pragma unroll
  for (int j = 0; j < 4; ++j)
#pragma unroll
    for (int i = 0; i < 4; ++i)
      o_acc[i][j] = mfma16_bf16(vf[i], pfB[j], o_acc[i][j]);

  // ---- l reduction: quad-sum (kv within wave) then cross-wave via LDS ----
#pragma unroll
  for (int j = 0; j < 4; ++j) {
    float s = l_part[j];
    s += __shfl_xor(s, 16, 64);
    s += __shfl_xor(s, 32, 64);
    Lred[w][j * 16 + c16] = s;  // all quads write same value: benign
  }
  __syncthreads();
  float rl[4];
#pragma unroll
  for (int j = 0; j < 4; ++j) {
    int q = j * 16 + c16;
    rl[j] = 1.0f / (Lred[0][q] + Lred[1][q] + Lred[2][q] + Lred[3][q]);
  }

  // ---- O^T cross-wave reduction: 4 rounds, FULLY UNROLLED (static rd so
  // o_acc stays in registers - rule #20); round rd reduces d-tile rd, owned
  // by wave rd (normalize + pack + store). Banks: 2 lanes/bank (free). ----
#pragma unroll
  for (int rd = 0; rd < 4; ++rd) {
#pragma unroll
    for (int j = 0; j < 4; ++j)
#pragma unroll
      for (int r = 0; r < 4; ++r)
        Ored[(w * 16 + q4 * 4 + r) * ORST + j * 16 + c16] = o_acc[rd][j][r];
    __syncthreads();
    if (w == rd) {
#pragma unroll
      for (int j = 0; j < 4; ++j) {
        float v[4];
#pragma unroll
        for (int r = 0; r < 4; ++r) {
          int off = (q4 * 4 + r) * ORST + j * 16 + c16;
          v[r] = (Ored[off] + Ored[16 * ORST + off]) +
                 (Ored[32 * ORST + off] + Ored[48 * ORST + off]);
          v[r] *= rl[j];
        }
        bf16 b0 = __float2bfloat16(v[0]), b1 = __float2bfloat16(v[1]);
        bf16 b2 = __float2bfloat16(v[2]), b3 = __float2bfloat16(v[3]);
        short4 pk;
        pk.x = *(short*)&b0; pk.y = *(short*)&b1;
        pk.z = *(short*)&b2; pk.w = *(short*)&b3;
        // O[s0 + q][h*64 + d], d = rd*16 + q4*4 + r
        *(short4*)&O[(long)(s0 + j * 16 + c16) * HID + h * HL + rd * 16 + q4 * 4] = pk;
      }
    }
    __syncthreads();
  }
}

extern "C" void kernel_launch(void* const* d_in, const int* in_sizes, int n_in,
                              void* d_out, int out_size, void* d_ws, size_t ws_size,
                              hipStream_t stream) {
  const float* x = (const float*)d_in[0];
  const float* wq = (const float*)d_in[1];
  const float* wk = (const float*)d_in[2];
  const float* wv = (const float*)d_in[3];
  const float* wfc = (const float*)d_in[4];
  float* out = (float*)d_out;

  const long NBIG = (long)S_LEN * HID * sizeof(bf16);
  const long NWB = (long)HID * HID * sizeof(bf16);
  char* p = (char*)d_ws;
  bf16* xb = (bf16*)p;   p += NBIG;
  bf16* wqb = (bf16*)p;  p += NWB;
  bf16* wkb = (bf16*)p;  p += NWB;
  bf16* wvb = (bf16*)p;  p += NWB;
  bf16* wfcb = (bf16*)p; p += NWB;
  bf16* Qb = (bf16*)p;   p += NBIG;
  bf16* Kb = (bf16*)p;   p += NBIG;
  bf16* Vb = (bf16*)p;   p += NBIG;
  bf16* Vtb = (bf16*)p;  p += NBIG;
  bf16* Ob = (bf16*)p;   p += NBIG;

  const float c1 = 0.125f * 1.44269504088896340736f;  // softmax scale * log2(e)

  const long total4 = ((long)S_LEN * HID + 4L * HID * HID) / 4;
  cvt_all<<<(int)(total4 / 256), 256, 0, stream>>>(x, wq, wk, wv, wfc, xb, wqb, wkb,
                                                   wvb, wfcb);
  gemm_bt<bf16><<<dim3(HID / 128, S_LEN / 128, 3), 256, 0, stream>>>(
      xb, wqb, wkb, wvb, Qb, Kb, Vb, c1);
  transpose_v<<<dim3(S_LEN / 64, HID / 64), 256, 0, stream>>>(Vb, Vtb);
  flash_attn<<<dim3(S_LEN / QB * NHEAD), 256, 0, stream>>>(Qb, Kb, Vtb, Ob);
  gemm_fc<<<dim3(HID / 64, S_LEN / 128), 256, 0, stream>>>(Ob, wfcb, out);
}